// Round 11
// baseline (228.761 us; speedup 1.0000x reference)
//
#include <hip/hip_runtime.h>
#include <math.h>

#define N_ATOMS 4096
#define L_WORDS 65536
#define DD 10
#define HALO 11

#define CONV_BLOCKS 256
#define CONV_BLOCK 256
#define RPW 4                     // rows per wave
#define RPB 16                    // rows per block (4 waves x 4 rows)
#define QCOLS 1024                // columns per quarter
#define GNN_BLOCKS 1024           // 256 row-groups x 4 quarters
#define TOTAL_BLOCKS 1280         // 256 conv + 1024 gnn
#define ATT_BLOCKS 64
#define SH_FLOATS 16384           // 64 KB: 4 waves x 4096-float A stripes

// ---------------------------------------------------------------------------
// K0: embedding gather -> xs0 planes + hs0 = relu(W0 xs0 + b0) planes.
// ---------------------------------------------------------------------------
__global__ __launch_bounds__(128) void gnn_embed(
    const int* __restrict__ fp, const float* __restrict__ embed_fp,
    const float* __restrict__ Wg, const float* __restrict__ bg,
    float* __restrict__ xs, float* __restrict__ hs)
{
    const int n = blockIdx.x * 128 + threadIdx.x;   // grid 32x128 = 4096
    float x[DD];
    const float* e = embed_fp + (size_t)fp[n] * DD;
    #pragma unroll
    for (int d = 0; d < DD; ++d) x[d] = e[d];
    #pragma unroll
    for (int d = 0; d < DD; ++d) xs[d * N_ATOMS + n] = x[d];
    #pragma unroll
    for (int d = 0; d < DD; ++d) {
        float v = bg[d];
        #pragma unroll
        for (int k = 0; k < DD; ++k) v += Wg[d * DD + k] * x[k];
        hs[d * N_ATOMS + n] = fmaxf(v, 0.f);
    }
}

// ---------------------------------------------------------------------------
// K_prep: xs_{i+1} = xs_i + sum_q part_i ; hs_{i+1} = relu(W xs + b).
// ---------------------------------------------------------------------------
__global__ __launch_bounds__(128) void gnn_prep(
    const float* __restrict__ xs_in, const float* __restrict__ part,
    const float* __restrict__ Wg, const float* __restrict__ bg,
    float* __restrict__ xs_out, float* __restrict__ hs)
{
    const int n = blockIdx.x * 128 + threadIdx.x;   // grid 32x128
    float x[DD];
    #pragma unroll
    for (int d = 0; d < DD; ++d) {
        float v = xs_in[d * N_ATOMS + n];
        #pragma unroll
        for (int q = 0; q < 4; ++q)
            v += part[((size_t)q * DD + d) * N_ATOMS + n];
        x[d] = v;
        xs_out[d * N_ATOMS + n] = v;
    }
    #pragma unroll
    for (int d = 0; d < DD; ++d) {
        float v = bg[d];
        #pragma unroll
        for (int k = 0; k < DD; ++k) v += Wg[d * DD + k] * x[k];
        hs[d * N_ATOMS + n] = fmaxf(v, 0.f);
    }
}

// ---------------------------------------------------------------------------
// conv stage: one CNN layer over this block's 256 words.
// If hpb != null, also fuses hp = relu(Wa·relu(acc)+ba) for its own words.
// ---------------------------------------------------------------------------
__device__ __forceinline__ void conv_stage(
    float* sh, const int tid, const int bx,
    const float* __restrict__ tin, const int* __restrict__ words,
    const float* __restrict__ embed_word, const float* __restrict__ w,
    const float* __restrict__ bptr, float* __restrict__ tout,
    const float* __restrict__ Wa, const float* __restrict__ ba,
    float* __restrict__ hpb)
{
    const int l0 = bx * CONV_BLOCK;
    for (int idx = tid; idx < (CONV_BLOCK + 2 * HALO) * DD; idx += CONV_BLOCK) {
        int rr = idx / DD, d = idx - rr * DD;
        int gr = l0 - HALO + rr;
        float v = 0.f;
        if (gr >= 0 && gr < L_WORDS) {
            if (tin) v = tin[(size_t)gr * DD + d];
            else     v = embed_word[(size_t)words[gr] * DD + d];
        }
        sh[rr * 11 + d] = v;
    }
    __syncthreads();

    const float bias = *bptr;
    float acc[DD];
    #pragma unroll
    for (int d = 0; d < DD; ++d) acc[d] = bias;
    for (int i = 0; i < 23; ++i) {
        float row[DD];
        const float* sr = &sh[(tid + i) * 11];
        #pragma unroll
        for (int c = 0; c < DD; ++c) row[c] = sr[c];
        #pragma unroll
        for (int d = 0; d < DD; ++d) {
            #pragma unroll
            for (int c = 0; c < DD; ++c)
                acc[d] += row[c] * w[i * 23 + (c - d + 11)];
        }
    }
    const int l = l0 + tid;
    if (tout) {
        #pragma unroll
        for (int d = 0; d < DD; ++d)
            tout[(size_t)l * DD + d] = fmaxf(acc[d], 0.f);
    }
    if (hpb) {
        float xsp[DD];
        #pragma unroll
        for (int d = 0; d < DD; ++d) xsp[d] = fmaxf(acc[d], 0.f);
        #pragma unroll
        for (int d = 0; d < DD; ++d) {
            float v = ba[d];
            #pragma unroll
            for (int k = 0; k < DD; ++k) v += Wa[d * DD + k] * xsp[k];
            hpb[(size_t)l * DD + d] = fmaxf(v, 0.f);
        }
    }
}

// ---------------------------------------------------------------------------
// gnn stage: A@hs partial over a 1024-col quarter, 16 rows/block.
// THIS ROUND: A staged via async global_load_lds — each wave issues 16x1KB
// DMA copies (16 KB in flight, no VGPRs consumed) into its private LDS
// region, waits vmcnt(0) once, then computes from LDS. Fixes the measured
// in-flight-bytes bound (~1 KB/CU -> ~2 TB/s in R5-R10; now 128 KB/CU).
// A passes through LDS bit-exactly -> results unchanged.
// ---------------------------------------------------------------------------
__device__ __forceinline__ void gnn_stage(
    float* sh, const int tid, const int b,
    const float* __restrict__ hs,        // SoA [10][4096]
    const float* __restrict__ A, float* __restrict__ part_out)
{
    const int wave = tid >> 6, lane = tid & 63;
    const int q = b & 3, rg = b >> 2;    // rg 0..255
    const int r0 = rg * RPB + wave * RPW;

    float* myA = sh + wave * 4096;       // this wave's 16 KB stripe buffer

    // ---- async stage: 4 rows x 1024 cols, 16 issues of 1 KB each ----
    #pragma unroll
    for (int r = 0; r < RPW; ++r) {
        const float* grow = A + (size_t)(r0 + r) * N_ATOMS + q * QCOLS + lane * 4;
        float* lrow = myA + r * 1024;                    // wave-uniform base
        #pragma unroll
        for (int seg = 0; seg < 4; ++seg) {
            __builtin_amdgcn_global_load_lds(
                (const __attribute__((address_space(1))) void*)(grow + seg * 256),
                (__attribute__((address_space(3))) void*)(lrow + seg * 256),
                16, 0, 0);
        }
    }

    const float4* h4 = (const float4*)hs + q * (QCOLS / 4);

    asm volatile("s_waitcnt vmcnt(0)" ::: "memory");

    const float4* a4 = (const float4*)myA;   // [4][256] float4, conflict-free
    float acc[RPW][DD];
    #pragma unroll
    for (int r = 0; r < RPW; ++r)
        #pragma unroll
        for (int d = 0; d < DD; ++d) acc[r][d] = 0.f;

    #pragma unroll 1
    for (int it = 0; it < 4; ++it) {
        const int cb = it * 64 + lane;
        float4 a[RPW];
        #pragma unroll
        for (int r = 0; r < RPW; ++r) a[r] = a4[r * 256 + cb];
        #pragma unroll
        for (int d = 0; d < DD; ++d) {
            float4 h = h4[d * (N_ATOMS / 4) + cb];   // L2 hit, coalesced
            #pragma unroll
            for (int r = 0; r < RPW; ++r) {
                acc[r][d] += a[r].x * h.x;
                acc[r][d] += a[r].y * h.y;
                acc[r][d] += a[r].z * h.z;
                acc[r][d] += a[r].w * h.w;
            }
        }
    }

    // ---- reduction: 3 xor steps within 8-lane groups ----
    #pragma unroll
    for (int m = 1; m <= 4; m <<= 1) {
        #pragma unroll
        for (int r = 0; r < RPW; ++r)
            #pragma unroll
            for (int d = 0; d < DD; ++d)
                acc[r][d] += __shfl_xor(acc[r][d], m, 64);
    }

    // leaders stash partials into own (consumed) A region: [g][40]
    if ((lane & 7) == 0) {
        const int g = lane >> 3;
        float* dst = myA + g * 40;
        #pragma unroll
        for (int r = 0; r < RPW; ++r)
            #pragma unroll
            for (int d = 0; d < DD; ++d) dst[r * DD + d] = acc[r][d];
    }
    __syncthreads();

    // block finish: 160 outputs (10 planes x 16 rows), SoA coalesced write
    float* pdst = part_out + (size_t)q * DD * N_ATOMS + (size_t)rg * RPB;
    for (int o = tid; o < RPB * DD; o += 256) {
        const int d = o >> 4, rr = o & 15;
        const int w8 = rr >> 2, r = rr & 3;
        float v = 0.f;
        #pragma unroll
        for (int g = 0; g < 8; ++g)
            v += sh[w8 * 4096 + g * 40 + r * DD + d];
        pdst[d * N_ATOMS + rr] = v;
    }
}

// ---------------------------------------------------------------------------
// F: one pipeline step. blocks [0,256): conv layer; [256,1280): gnn layer.
// LDS 64 KB/block -> 2 blocks/CU; latency hidden by DMA depth, not waves.
// ---------------------------------------------------------------------------
__global__ __launch_bounds__(256) void fused_layer(
    const float* __restrict__ A, const float* __restrict__ hs,
    float* __restrict__ part_out,
    const float* __restrict__ tin, const int* __restrict__ words,
    const float* __restrict__ emb_w, const float* __restrict__ wc,
    const float* __restrict__ bc, float* __restrict__ tout,
    const float* __restrict__ Wa, const float* __restrict__ ba,
    float* __restrict__ hpb)
{
    __shared__ float sh[SH_FLOATS];      // 64 KB
    const int tid = threadIdx.x;
    if (blockIdx.x < CONV_BLOCKS)
        conv_stage(sh, tid, blockIdx.x, tin, words, emb_w, wc, bc, tout,
                   Wa, ba, hpb);
    else
        gnn_stage(sh, tid, blockIdx.x - CONV_BLOCKS, hs, A, part_out);
}

// ---------------------------------------------------------------------------
// ATTN+FINAL: 64 blocks x 1024 threads (1 word/thread). Relaxed agent-scope
// atomic publication + last-block ticket election (proven rounds 4-10).
// ---------------------------------------------------------------------------
__global__ __launch_bounds__(1024) void attn_final(
    const float* __restrict__ xs2, const float* __restrict__ part2,
    const float* __restrict__ hpb,
    const float* __restrict__ Wa, const float* __restrict__ ba,
    const float* __restrict__ Wo, const float* __restrict__ bo,
    const float* __restrict__ Wi, const float* __restrict__ bi,
    float* att_part, unsigned int* ticket, float* __restrict__ out)
{
    __shared__ float red[16][DD];
    __shared__ float shc[DD];
    __shared__ float cat[20];
    __shared__ int islast;
    const int tid = threadIdx.x, wave = tid >> 6, lane = tid & 63;

    float c[DD];
    #pragma unroll
    for (int d = 0; d < DD; ++d) c[d] = 0.f;
    #pragma unroll
    for (int s = 0; s < 4; ++s) {
        const int n = s * 1024 + tid;
        #pragma unroll
        for (int d = 0; d < DD; ++d) {
            float v = xs2[d * N_ATOMS + n];
            #pragma unroll
            for (int qq = 0; qq < 4; ++qq)
                v += part2[((size_t)qq * DD + d) * N_ATOMS + n];
            c[d] += v;
        }
    }
    #pragma unroll
    for (int m = 32; m >= 1; m >>= 1) {
        #pragma unroll
        for (int d = 0; d < DD; ++d) c[d] += __shfl_xor(c[d], m, 64);
    }
    if (lane == 0) {
        #pragma unroll
        for (int d = 0; d < DD; ++d) red[wave][d] = c[d];
    }
    __syncthreads();
    if (tid < DD) {
        float v = 0.f;
        #pragma unroll
        for (int w = 0; w < 16; ++w) v += red[w][tid];
        shc[tid] = v * (1.f / N_ATOMS);
    }
    __syncthreads();

    float h[DD];
    #pragma unroll
    for (int d = 0; d < DD; ++d) {
        float v = ba[d];
        #pragma unroll
        for (int k = 0; k < DD; ++k) v += Wa[d * DD + k] * shc[k];
        h[d] = fmaxf(v, 0.f);
    }
    const int w_ = blockIdx.x * 1024 + tid;
    float hp[DD], dotv = 0.f;
    #pragma unroll
    for (int d = 0; d < DD; ++d) {
        hp[d] = hpb[(size_t)w_ * DD + d];
        dotv += h[d] * hp[d];
    }
    const float wgt = tanhf(dotv);
    float y[DD];
    #pragma unroll
    for (int d = 0; d < DD; ++d) y[d] = wgt * hp[d];
    #pragma unroll
    for (int m = 32; m >= 1; m >>= 1) {
        #pragma unroll
        for (int d = 0; d < DD; ++d) y[d] += __shfl_xor(y[d], m, 64);
    }
    __syncthreads();
    if (lane == 0) {
        #pragma unroll
        for (int d = 0; d < DD; ++d) red[wave][d] = y[d];
    }
    __syncthreads();
    if (tid < DD) {
        float v = 0.f;
        #pragma unroll
        for (int w = 0; w < 16; ++w) v += red[w][tid];
        __hip_atomic_store(att_part + blockIdx.x * DD + tid, v,
                           __ATOMIC_RELAXED, __HIP_MEMORY_SCOPE_AGENT);
    }
    __syncthreads();

    if (tid == 0) {
        unsigned prev = __hip_atomic_fetch_add(ticket, 1u, __ATOMIC_RELAXED,
                                               __HIP_MEMORY_SCOPE_AGENT);
        islast = (prev == ATT_BLOCKS - 1);
    }
    __syncthreads();
    if (!islast) return;
    asm volatile("" ::: "memory");

    float a[DD];
    #pragma unroll
    for (int d = 0; d < DD; ++d) a[d] = 0.f;
    if (tid < ATT_BLOCKS) {
        #pragma unroll
        for (int d = 0; d < DD; ++d)
            a[d] = __hip_atomic_load(att_part + tid * DD + d,
                                     __ATOMIC_RELAXED, __HIP_MEMORY_SCOPE_AGENT);
    }
    if (wave == 0) {
        #pragma unroll
        for (int m = 32; m >= 1; m >>= 1) {
            #pragma unroll
            for (int d = 0; d < DD; ++d) a[d] += __shfl_xor(a[d], m, 64);
        }
    }
    if (tid == 0) {
        #pragma unroll
        for (int d = 0; d < DD; ++d) cat[DD + d] = a[d] * (1.f / L_WORDS);
    }
    if (tid < DD) cat[tid] = shc[tid];
    __syncthreads();
    for (int j = 0; j < 3; ++j) {
        float v = 0.f;
        if (tid < 20) {
            v = bo[j * 20 + tid];
            for (int k = 0; k < 20; ++k) v += Wo[j * 400 + tid * 20 + k] * cat[k];
        }
        __syncthreads();
        if (tid < 20) cat[tid] = fmaxf(v, 0.f);
        __syncthreads();
    }
    if (tid < 2) {
        float v = bi[tid];
        for (int k = 0; k < 20; ++k) v += Wi[tid * 20 + k] * cat[k];
        out[tid] = v;
    }
}

// ---------------------------------------------------------------------------
extern "C" void kernel_launch(void* const* d_in, const int* in_sizes, int n_in,
                              void* d_out, int out_size, void* d_ws, size_t ws_size,
                              hipStream_t stream)
{
    const int*   fp     = (const int*)d_in[0];
    const float* A      = (const float*)d_in[1];
    const int*   words  = (const int*)d_in[2];
    const float* emb_fp = (const float*)d_in[3];
    const float* emb_w  = (const float*)d_in[4];
    const float* Wg     = (const float*)d_in[5];   // [3][10][10]
    const float* bg     = (const float*)d_in[6];   // [3][10]
    const float* Wc     = (const float*)d_in[7];   // [3][529]
    const float* bc     = (const float*)d_in[8];   // [3]
    const float* Wa     = (const float*)d_in[9];   // [10][10]
    const float* ba     = (const float*)d_in[10];  // [10]
    const float* Wo     = (const float*)d_in[11];  // [3][20][20]
    const float* bo     = (const float*)d_in[12];  // [3][20]
    const float* Wi     = (const float*)d_in[13];  // [2][20]
    const float* bi     = (const float*)d_in[14];  // [2]
    float* out = (float*)d_out;
    float* ws  = (float*)d_ws;

    float* xs0   = ws;                       // 40960   SoA [10][4096]
    float* xs1   = ws + 40960;               // 40960
    float* xs2   = ws + 81920;               // 40960
    float* hs0   = ws + 122880;              // 40960   SoA planes
    float* hs1   = ws + 163840;              // 40960
    float* hs2   = ws + 204800;              // 40960
    float* part0 = ws + 245760;              // 163840  SoA [4][10][4096]
    float* part1 = ws + 409600;              // 163840
    float* part2 = ws + 573440;              // 163840
    float* ta    = ws + 737280;              // 655360
    float* tb    = ws + 1392640;             // 655360
    float* hpb   = ta;                       // alias: ta dead after F1 reads it
    float* att_part = ws + 2048000;          // 640
    unsigned int* ticket = (unsigned int*)(ws + 2048640);

    hipMemsetAsync(ticket, 0, sizeof(unsigned int), stream);

    // K0: embed gather once (tiny) -> xs0 + hs0 planes
    gnn_embed<<<N_ATOMS / 128, 128, 0, stream>>>(fp, emb_fp, Wg, bg, xs0, hs0);

    // F0: conv-L0 || gnn-L0
    fused_layer<<<TOTAL_BLOCKS, 256, 0, stream>>>(
        A, hs0, part0,
        nullptr, words, emb_w, Wc, bc, ta, nullptr, nullptr, nullptr);

    // P1: xs1 = xs0 + sum part0 ; hs1 = relu(W1 xs1 + b1)
    gnn_prep<<<N_ATOMS / 128, 128, 0, stream>>>(
        xs0, part0, Wg + 100, bg + 10, xs1, hs1);

    // F1: conv-L1 || gnn-L1
    fused_layer<<<TOTAL_BLOCKS, 256, 0, stream>>>(
        A, hs1, part1,
        ta, words, emb_w, Wc + 529, bc + 1, tb, nullptr, nullptr, nullptr);

    // P2: xs2 = xs1 + sum part1 ; hs2 = relu(W2 xs2 + b2)
    gnn_prep<<<N_ATOMS / 128, 128, 0, stream>>>(
        xs1, part1, Wg + 200, bg + 20, xs2, hs2);

    // F2: conv-L2 (+ fused hp) || gnn-L2
    fused_layer<<<TOTAL_BLOCKS, 256, 0, stream>>>(
        A, hs2, part2,
        tb, words, emb_w, Wc + 1058, bc + 2, nullptr, Wa, ba, hpb);

    // ATTN (+ comp in-block, + final MLP in last-arriving block)
    attn_final<<<ATT_BLOCKS, 1024, 0, stream>>>(
        xs2, part2, hpb, Wa, ba, Wo, bo, Wi, bi, att_part, ticket, out);
}

// Round 12
// 208.275 us; speedup vs baseline: 1.0984x; 1.0984x over previous
//
#include <hip/hip_runtime.h>
#include <math.h>

#define N_ATOMS 4096
#define L_WORDS 65536
#define DD 10
#define HALO 11

#define CONV_BLOCKS 256
#define CONV_BLOCK 256
#define RPW 4                     // rows per wave
#define RPB 16                    // rows per block (4 waves x 4 rows)
#define QCOLS 1024                // columns per quarter
#define GNN_BLOCKS 1024           // 256 row-groups x 4 quarters
#define TOTAL_BLOCKS 1280         // 256 conv + 1024 gnn
#define ATT_BLOCKS 256
#define SH_FLOATS 2926            // max(conv halo 266*11 = 2926, stash 1280)

// ---------------------------------------------------------------------------
// K0: embedding gather -> xs0 planes + hs0 = relu(W0 xs0 + b0) planes.
// ---------------------------------------------------------------------------
__global__ __launch_bounds__(128) void gnn_embed(
    const int* __restrict__ fp, const float* __restrict__ embed_fp,
    const float* __restrict__ Wg, const float* __restrict__ bg,
    float* __restrict__ xs, float* __restrict__ hs)
{
    const int n = blockIdx.x * 128 + threadIdx.x;   // grid 32x128 = 4096
    float x[DD];
    const float* e = embed_fp + (size_t)fp[n] * DD;
    #pragma unroll
    for (int d = 0; d < DD; ++d) x[d] = e[d];
    #pragma unroll
    for (int d = 0; d < DD; ++d) xs[d * N_ATOMS + n] = x[d];
    #pragma unroll
    for (int d = 0; d < DD; ++d) {
        float v = bg[d];
        #pragma unroll
        for (int k = 0; k < DD; ++k) v += Wg[d * DD + k] * x[k];
        hs[d * N_ATOMS + n] = fmaxf(v, 0.f);
    }
}

// ---------------------------------------------------------------------------
// K_prep: xs_{i+1} = xs_i + sum_q part_i ; hs_{i+1} = relu(W xs + b).
// ---------------------------------------------------------------------------
__global__ __launch_bounds__(128) void gnn_prep(
    const float* __restrict__ xs_in, const float* __restrict__ part,
    const float* __restrict__ Wg, const float* __restrict__ bg,
    float* __restrict__ xs_out, float* __restrict__ hs)
{
    const int n = blockIdx.x * 128 + threadIdx.x;   // grid 32x128
    float x[DD];
    #pragma unroll
    for (int d = 0; d < DD; ++d) {
        float v = xs_in[d * N_ATOMS + n];
        #pragma unroll
        for (int q = 0; q < 4; ++q)
            v += part[((size_t)q * DD + d) * N_ATOMS + n];
        x[d] = v;
        xs_out[d * N_ATOMS + n] = v;
    }
    #pragma unroll
    for (int d = 0; d < DD; ++d) {
        float v = bg[d];
        #pragma unroll
        for (int k = 0; k < DD; ++k) v += Wg[d * DD + k] * x[k];
        hs[d * N_ATOMS + n] = fmaxf(v, 0.f);
    }
}

// ---------------------------------------------------------------------------
// conv stage: one CNN layer over this block's 256 words.
// If hpb != null, also fuses hp = relu(Wa·relu(acc)+ba) for its own words.
// ---------------------------------------------------------------------------
__device__ __forceinline__ void conv_stage(
    float* sh, const int tid, const int bx,
    const float* __restrict__ tin, const int* __restrict__ words,
    const float* __restrict__ embed_word, const float* __restrict__ w,
    const float* __restrict__ bptr, float* __restrict__ tout,
    const float* __restrict__ Wa, const float* __restrict__ ba,
    float* __restrict__ hpb)
{
    const int l0 = bx * CONV_BLOCK;
    for (int idx = tid; idx < (CONV_BLOCK + 2 * HALO) * DD; idx += CONV_BLOCK) {
        int rr = idx / DD, d = idx - rr * DD;
        int gr = l0 - HALO + rr;
        float v = 0.f;
        if (gr >= 0 && gr < L_WORDS) {
            if (tin) v = tin[(size_t)gr * DD + d];
            else     v = embed_word[(size_t)words[gr] * DD + d];
        }
        sh[rr * 11 + d] = v;
    }
    __syncthreads();

    const float bias = *bptr;
    float acc[DD];
    #pragma unroll
    for (int d = 0; d < DD; ++d) acc[d] = bias;
    for (int i = 0; i < 23; ++i) {
        float row[DD];
        const float* sr = &sh[(tid + i) * 11];
        #pragma unroll
        for (int c = 0; c < DD; ++c) row[c] = sr[c];
        #pragma unroll
        for (int d = 0; d < DD; ++d) {
            #pragma unroll
            for (int c = 0; c < DD; ++c)
                acc[d] += row[c] * w[i * 23 + (c - d + 11)];
        }
    }
    const int l = l0 + tid;
    if (tout) {
        #pragma unroll
        for (int d = 0; d < DD; ++d)
            tout[(size_t)l * DD + d] = fmaxf(acc[d], 0.f);
    }
    if (hpb) {
        float xsp[DD];
        #pragma unroll
        for (int d = 0; d < DD; ++d) xsp[d] = fmaxf(acc[d], 0.f);
        #pragma unroll
        for (int d = 0; d < DD; ++d) {
            float v = ba[d];
            #pragma unroll
            for (int k = 0; k < DD; ++k) v += Wa[d * DD + k] * xsp[k];
            hpb[(size_t)l * DD + d] = fmaxf(v, 0.f);
        }
    }
}

// ---------------------------------------------------------------------------
// gnn stage: A@hs partial over a 1024-col quarter, 16 rows/block.
// THIS ROUND: main loop FULLY UNROLLED (was #pragma unroll 1 all session) —
// lets hipcc software-pipeline the 16 A-loads + 40 h-loads across iterations
// with counted waitcnts instead of a per-iteration drain. Fits registers at
// RPW=4 under the (256,4) 128-VGPR cap (R6's spill was RPW=8 + manual bufs).
// ---------------------------------------------------------------------------
__device__ __forceinline__ void gnn_stage(
    float* sh, const int tid, const int b,
    const float* __restrict__ hs,        // SoA [10][4096]
    const float* __restrict__ A, float* __restrict__ part_out)
{
    const int wave = tid >> 6, lane = tid & 63;
    const int q = b & 3, rg = b >> 2;    // rg 0..255

    const int r0 = rg * RPB + wave * RPW;
    const float4* A4 = (const float4*)(A + (size_t)r0 * N_ATOMS) + q * (QCOLS / 4);
    const float4* h4 = (const float4*)hs + q * (QCOLS / 4);

    float acc[RPW][DD];
    #pragma unroll
    for (int r = 0; r < RPW; ++r)
        #pragma unroll
        for (int d = 0; d < DD; ++d) acc[r][d] = 0.f;

    #pragma unroll
    for (int it = 0; it < 4; ++it) {
        const int cb = it * 64 + lane;
        float4 a[RPW];
        #pragma unroll
        for (int r = 0; r < RPW; ++r) a[r] = A4[r * (N_ATOMS / 4) + cb];
        #pragma unroll
        for (int d = 0; d < DD; ++d) {
            float4 h = h4[d * (N_ATOMS / 4) + cb];   // L2 hit, coalesced
            #pragma unroll
            for (int r = 0; r < RPW; ++r) {
                acc[r][d] += a[r].x * h.x;
                acc[r][d] += a[r].y * h.y;
                acc[r][d] += a[r].z * h.z;
                acc[r][d] += a[r].w * h.w;
            }
        }
    }

    // ---- reduction: 3 xor steps within 8-lane groups ----
    #pragma unroll
    for (int m = 1; m <= 4; m <<= 1) {
        #pragma unroll
        for (int r = 0; r < RPW; ++r)
            #pragma unroll
            for (int d = 0; d < DD; ++d)
                acc[r][d] += __shfl_xor(acc[r][d], m, 64);
    }

    // leaders stash partials: [wave][group][40]
    if ((lane & 7) == 0) {
        const int g = lane >> 3;
        float* dst = &sh[(wave * 8 + g) * 40];
        #pragma unroll
        for (int r = 0; r < RPW; ++r)
            #pragma unroll
            for (int d = 0; d < DD; ++d) dst[r * DD + d] = acc[r][d];
    }
    __syncthreads();

    // block finish: 160 outputs (10 planes x 16 rows), SoA coalesced write
    float* pdst = part_out + (size_t)q * DD * N_ATOMS + (size_t)rg * RPB;
    for (int o = tid; o < RPB * DD; o += 256) {
        const int d = o >> 4, rr = o & 15;
        const int w8 = rr >> 2, r = rr & 3;
        float v = 0.f;
        #pragma unroll
        for (int g = 0; g < 8; ++g) v += sh[(w8 * 8 + g) * 40 + r * DD + d];
        pdst[d * N_ATOMS + rr] = v;
    }
}

// ---------------------------------------------------------------------------
// F: one pipeline step. blocks [0,256): conv layer; [256,1280): gnn layer.
// ---------------------------------------------------------------------------
__global__ __launch_bounds__(256, 4) void fused_layer(
    const float* __restrict__ A, const float* __restrict__ hs,
    float* __restrict__ part_out,
    const float* __restrict__ tin, const int* __restrict__ words,
    const float* __restrict__ emb_w, const float* __restrict__ wc,
    const float* __restrict__ bc, float* __restrict__ tout,
    const float* __restrict__ Wa, const float* __restrict__ ba,
    float* __restrict__ hpb)
{
    __shared__ float sh[SH_FLOATS];      // 11.7 KB
    const int tid = threadIdx.x;
    if (blockIdx.x < CONV_BLOCKS)
        conv_stage(sh, tid, blockIdx.x, tin, words, emb_w, wc, bc, tout,
                   Wa, ba, hpb);
    else
        gnn_stage(sh, tid, blockIdx.x - CONV_BLOCKS, hs, A, part_out);
}

// ---------------------------------------------------------------------------
// K_comp: comp partials computed ONCE (16 blocks x 256 atoms) -> comp_part.
// Removes the 51 MB of redundant per-block comp re-reads attn_final did.
// ---------------------------------------------------------------------------
__global__ __launch_bounds__(256) void comp_reduce(
    const float* __restrict__ xs, const float* __restrict__ p2,
    float* __restrict__ comp_part)
{
    const int tid = threadIdx.x, wave = tid >> 6, lane = tid & 63;
    const int n = blockIdx.x * 256 + tid;
    float x[DD];
    #pragma unroll
    for (int d = 0; d < DD; ++d) {
        float v = xs[d * N_ATOMS + n];
        #pragma unroll
        for (int qq = 0; qq < 4; ++qq)
            v += p2[((size_t)qq * DD + d) * N_ATOMS + n];
        x[d] = v;
    }
    #pragma unroll
    for (int m = 32; m >= 1; m >>= 1) {
        #pragma unroll
        for (int d = 0; d < DD; ++d) x[d] += __shfl_xor(x[d], m, 64);
    }
    __shared__ float s[4][DD];
    if (lane == 0) {
        #pragma unroll
        for (int d = 0; d < DD; ++d) s[wave][d] = x[d];
    }
    __syncthreads();
    if (tid < DD)
        comp_part[blockIdx.x * DD + tid] =
            s[0][tid] + s[1][tid] + s[2][tid] + s[3][tid];
}

// ---------------------------------------------------------------------------
// ATTN+FINAL: 256 blocks x 256 threads (1 word/thread, full machine).
// comp read from comp_part (640 B). Relaxed agent-scope atomic publication +
// last-block ticket election (proven rounds 4-11).
// ---------------------------------------------------------------------------
__global__ __launch_bounds__(256) void attn_final(
    const float* __restrict__ comp_part, const float* __restrict__ hpb,
    const float* __restrict__ Wa, const float* __restrict__ ba,
    const float* __restrict__ Wo, const float* __restrict__ bo,
    const float* __restrict__ Wi, const float* __restrict__ bi,
    float* att_part, unsigned int* ticket, float* __restrict__ out)
{
    __shared__ float red[4][DD];
    __shared__ float shc[DD];
    __shared__ float cat[20];
    __shared__ int islast;
    const int tid = threadIdx.x, wave = tid >> 6, lane = tid & 63;

    if (tid < DD) {
        float c = 0.f;
        #pragma unroll
        for (int p = 0; p < 16; ++p) c += comp_part[p * DD + tid];
        shc[tid] = c * (1.f / N_ATOMS);
    }
    __syncthreads();

    float h[DD];
    #pragma unroll
    for (int d = 0; d < DD; ++d) {
        float v = ba[d];
        #pragma unroll
        for (int k = 0; k < DD; ++k) v += Wa[d * DD + k] * shc[k];
        h[d] = fmaxf(v, 0.f);
    }
    const int w_ = blockIdx.x * 256 + tid;
    float hp[DD], dotv = 0.f;
    #pragma unroll
    for (int d = 0; d < DD; ++d) {
        hp[d] = hpb[(size_t)w_ * DD + d];
        dotv += h[d] * hp[d];
    }
    const float wgt = tanhf(dotv);
    float y[DD];
    #pragma unroll
    for (int d = 0; d < DD; ++d) y[d] = wgt * hp[d];
    #pragma unroll
    for (int m = 32; m >= 1; m >>= 1) {
        #pragma unroll
        for (int d = 0; d < DD; ++d) y[d] += __shfl_xor(y[d], m, 64);
    }
    if (lane == 0) {
        #pragma unroll
        for (int d = 0; d < DD; ++d) red[wave][d] = y[d];
    }
    __syncthreads();
    if (tid < DD) {
        float v = red[0][tid] + red[1][tid] + red[2][tid] + red[3][tid];
        __hip_atomic_store(att_part + blockIdx.x * DD + tid, v,
                           __ATOMIC_RELAXED, __HIP_MEMORY_SCOPE_AGENT);
    }
    __syncthreads();   // drains each wave's vmcnt -> stores globally visible

    if (tid == 0) {
        unsigned prev = __hip_atomic_fetch_add(ticket, 1u, __ATOMIC_RELAXED,
                                               __HIP_MEMORY_SCOPE_AGENT);
        islast = (prev == ATT_BLOCKS - 1);
    }
    __syncthreads();
    if (!islast) return;
    asm volatile("" ::: "memory");

    // ---- final: reduce 256 partials (1 per thread) + MLP ----
    float a[DD];
    #pragma unroll
    for (int d = 0; d < DD; ++d)
        a[d] = __hip_atomic_load(att_part + tid * DD + d,
                                 __ATOMIC_RELAXED, __HIP_MEMORY_SCOPE_AGENT);
    #pragma unroll
    for (int m = 32; m >= 1; m >>= 1) {
        #pragma unroll
        for (int d = 0; d < DD; ++d) a[d] += __shfl_xor(a[d], m, 64);
    }
    __syncthreads();                 // red[] reuse
    if (lane == 0) {
        #pragma unroll
        for (int d = 0; d < DD; ++d) red[wave][d] = a[d];
    }
    __syncthreads();
    if (tid < DD) {
        float pv = red[0][tid] + red[1][tid] + red[2][tid] + red[3][tid];
        cat[DD + tid] = pv * (1.f / L_WORDS);
        cat[tid] = shc[tid];
    }
    __syncthreads();
    for (int j = 0; j < 3; ++j) {
        float v = 0.f;
        if (tid < 20) {
            v = bo[j * 20 + tid];
            for (int k = 0; k < 20; ++k) v += Wo[j * 400 + tid * 20 + k] * cat[k];
        }
        __syncthreads();
        if (tid < 20) cat[tid] = fmaxf(v, 0.f);
        __syncthreads();
    }
    if (tid < 2) {
        float v = bi[tid];
        for (int k = 0; k < 20; ++k) v += Wi[tid * 20 + k] * cat[k];
        out[tid] = v;
    }
}

// ---------------------------------------------------------------------------
extern "C" void kernel_launch(void* const* d_in, const int* in_sizes, int n_in,
                              void* d_out, int out_size, void* d_ws, size_t ws_size,
                              hipStream_t stream)
{
    const int*   fp     = (const int*)d_in[0];
    const float* A      = (const float*)d_in[1];
    const int*   words  = (const int*)d_in[2];
    const float* emb_fp = (const float*)d_in[3];
    const float* emb_w  = (const float*)d_in[4];
    const float* Wg     = (const float*)d_in[5];   // [3][10][10]
    const float* bg     = (const float*)d_in[6];   // [3][10]
    const float* Wc     = (const float*)d_in[7];   // [3][529]
    const float* bc     = (const float*)d_in[8];   // [3]
    const float* Wa     = (const float*)d_in[9];   // [10][10]
    const float* ba     = (const float*)d_in[10];  // [10]
    const float* Wo     = (const float*)d_in[11];  // [3][20][20]
    const float* bo     = (const float*)d_in[12];  // [3][20]
    const float* Wi     = (const float*)d_in[13];  // [2][20]
    const float* bi     = (const float*)d_in[14];  // [2]
    float* out = (float*)d_out;
    float* ws  = (float*)d_ws;

    float* xs0   = ws;                       // 40960   SoA [10][4096]
    float* xs1   = ws + 40960;               // 40960
    float* xs2   = ws + 81920;               // 40960
    float* hs0   = ws + 122880;              // 40960   SoA planes
    float* hs1   = ws + 163840;              // 40960
    float* hs2   = ws + 204800;              // 40960
    float* part0 = ws + 245760;              // 163840  SoA [4][10][4096]
    float* part1 = ws + 409600;              // 163840
    float* part2 = ws + 573440;              // 163840
    float* ta    = ws + 737280;              // 655360
    float* tb    = ws + 1392640;             // 655360
    float* hpb   = ta;                       // alias: ta dead after F1 reads it
    float* att_part  = ws + 2048000;         // 2560 (256 x 10)
    float* comp_part = ws + 2050560;         // 160
    unsigned int* ticket = (unsigned int*)(ws + 2050720);

    hipMemsetAsync(ticket, 0, sizeof(unsigned int), stream);

    // K0: embed gather once (tiny) -> xs0 + hs0 planes
    gnn_embed<<<N_ATOMS / 128, 128, 0, stream>>>(fp, emb_fp, Wg, bg, xs0, hs0);

    // F0: conv-L0 || gnn-L0
    fused_layer<<<TOTAL_BLOCKS, 256, 0, stream>>>(
        A, hs0, part0,
        nullptr, words, emb_w, Wc, bc, ta, nullptr, nullptr, nullptr);

    // P1: xs1 = xs0 + sum part0 ; hs1 = relu(W1 xs1 + b1)
    gnn_prep<<<N_ATOMS / 128, 128, 0, stream>>>(
        xs0, part0, Wg + 100, bg + 10, xs1, hs1);

    // F1: conv-L1 || gnn-L1
    fused_layer<<<TOTAL_BLOCKS, 256, 0, stream>>>(
        A, hs1, part1,
        ta, words, emb_w, Wc + 529, bc + 1, tb, nullptr, nullptr, nullptr);

    // P2: xs2 = xs1 + sum part1 ; hs2 = relu(W2 xs2 + b2)
    gnn_prep<<<N_ATOMS / 128, 128, 0, stream>>>(
        xs1, part1, Wg + 200, bg + 20, xs2, hs2);

    // F2: conv-L2 (+ fused hp) || gnn-L2
    fused_layer<<<TOTAL_BLOCKS, 256, 0, stream>>>(
        A, hs2, part2,
        tb, words, emb_w, Wc + 1058, bc + 2, nullptr, Wa, ba, hpb);

    // comp partials once (tiny)
    comp_reduce<<<16, 256, 0, stream>>>(xs2, part2, comp_part);

    // ATTN over full machine (+ final MLP in last-arriving block)
    attn_final<<<ATT_BLOCKS, 256, 0, stream>>>(
        comp_part, hpb, Wa, ba, Wo, bo, Wi, bi, att_part, ticket, out);
}